// Round 1
// baseline (561.674 us; speedup 1.0000x reference)
//
#include <hip/hip_runtime.h>
#include <cstddef>

#define B_  32
#define C_  256
#define N_  1024   // 32*32 full-res spatial
#define M_  256    // 16*16 downsampled spatial
#define NH_ 8
#define DH_ 32

// ---------------------------------------------------------------------------
// Generic per-batch 1x1-conv GEMM: Y[b,o,n] = sum_c W[o,c] * X[b,c,n] (+bias[o])
// grid: (C_/64, NSP/64, B_), block 256.  64x64 tile, 4x4 per thread, K-chunk 16.
// ---------------------------------------------------------------------------
template<int NSP>
__global__ __launch_bounds__(256) void gemm1x1(
    const float* __restrict__ Wm, const float* __restrict__ X,
    const float* __restrict__ bias, float* __restrict__ Y)
{
    __shared__ float Ws[64][17];   // +1 pad: conflict-free scalar reads
    __shared__ float Xs[16][64];   // b128 reads are 2-way aliased (free)

    const int row0 = blockIdx.x * 64;
    const int n0   = blockIdx.y * 64;
    const int b    = blockIdx.z;
    const float* Xb = X + (size_t)b * C_ * NSP;
    float*       Yb = Y + (size_t)b * C_ * NSP;

    const int tid = threadIdx.x;
    const int ty = tid >> 4, tx = tid & 15;

    float acc[4][4];
    #pragma unroll
    for (int i = 0; i < 4; ++i)
        #pragma unroll
        for (int j = 0; j < 4; ++j) acc[i][j] = 0.f;

    const int wr = tid >> 2, wk = (tid & 3) * 4;   // W-tile: 64 rows x 16 k
    const int xk = tid >> 4, xn = (tid & 15) * 4;  // X-tile: 16 k x 64 n

    for (int k0 = 0; k0 < C_; k0 += 16) {
        float4 wv4 = *(const float4*)(Wm + (size_t)(row0 + wr) * C_ + k0 + wk);
        float4 xv4 = *(const float4*)(Xb + (size_t)(k0 + xk) * NSP + n0 + xn);
        Ws[wr][wk+0] = wv4.x; Ws[wr][wk+1] = wv4.y;
        Ws[wr][wk+2] = wv4.z; Ws[wr][wk+3] = wv4.w;
        *(float4*)&Xs[xk][xn] = xv4;
        __syncthreads();
        #pragma unroll
        for (int kk = 0; kk < 16; ++kk) {
            float a[4];
            #pragma unroll
            for (int i = 0; i < 4; ++i) a[i] = Ws[ty*4 + i][kk];
            float4 bx = *(const float4*)&Xs[kk][tx*4];
            float bb[4] = {bx.x, bx.y, bx.z, bx.w};
            #pragma unroll
            for (int i = 0; i < 4; ++i)
                #pragma unroll
                for (int j = 0; j < 4; ++j) acc[i][j] += a[i] * bb[j];
        }
        __syncthreads();
    }

    #pragma unroll
    for (int i = 0; i < 4; ++i) {
        const int row = row0 + ty*4 + i;
        const float bv = bias ? bias[row] : 0.f;
        float4 o;
        o.x = acc[i][0] + bv; o.y = acc[i][1] + bv;
        o.z = acc[i][2] + bv; o.w = acc[i][3] + bv;
        *(float4*)(Yb + (size_t)row * NSP + n0 + tx*4) = o;
    }
}

// ---------------------------------------------------------------------------
// Fused depthwise conv3x3 stride2 pad1 + GroupNorm(32 groups of 8ch) + SiLU
// One block per (b, group): 8 channels x 16x16 = 2048 elements, 256 threads.
// ---------------------------------------------------------------------------
__global__ __launch_bounds__(256) void dw_gn_silu(
    const float* __restrict__ in,   // (B,C,32,32)
    const float* __restrict__ dw,   // (C,3,3)
    const float* __restrict__ gs, const float* __restrict__ gb,
    float* __restrict__ out)        // (B,C,16,16)
{
    __shared__ float red[8];
    const int b = blockIdx.x >> 5;
    const int g = blockIdx.x & 31;
    const int tid = threadIdx.x;
    const int oy = tid >> 4, ox = tid & 15;
    const int iy0 = oy*2 - 1, ix0 = ox*2 - 1;

    float vals[8];
    float s1 = 0.f, s2 = 0.f;
    #pragma unroll
    for (int cc = 0; cc < 8; ++cc) {
        const int c = g*8 + cc;
        const float* ip = in + ((size_t)(b*C_ + c)) * 1024;
        const float* wp = dw + c*9;
        float s = 0.f;
        #pragma unroll
        for (int dy = 0; dy < 3; ++dy) {
            const int iy = iy0 + dy;
            if (iy < 0 || iy > 31) continue;
            #pragma unroll
            for (int dx = 0; dx < 3; ++dx) {
                const int ix = ix0 + dx;
                if (ix < 0 || ix > 31) continue;
                s += ip[iy*32 + ix] * wp[dy*3 + dx];
            }
        }
        vals[cc] = s;
        s1 += s; s2 += s*s;
    }
    #pragma unroll
    for (int off = 32; off > 0; off >>= 1) {
        s1 += __shfl_down(s1, off);
        s2 += __shfl_down(s2, off);
    }
    const int lane = tid & 63, wid = tid >> 6;
    if (lane == 0) { red[wid] = s1; red[4 + wid] = s2; }
    __syncthreads();
    s1 = red[0] + red[1] + red[2] + red[3];
    s2 = red[4] + red[5] + red[6] + red[7];
    const float mean = s1 * (1.f/2048.f);
    const float var  = s2 * (1.f/2048.f) - mean*mean;
    const float rstd = rsqrtf(var + 1e-5f);
    #pragma unroll
    for (int cc = 0; cc < 8; ++cc) {
        const int c = g*8 + cc;
        const float xn = (vals[cc] - mean) * rstd * gs[c] + gb[c];
        const float y  = xn / (1.f + __expf(-xn));
        out[((size_t)(b*C_ + c)) * 256 + tid] = y;
    }
}

// ---------------------------------------------------------------------------
// In-place GroupNorm + SiLU on (B,C,16,16). One block per (b,group).
// ---------------------------------------------------------------------------
__global__ __launch_bounds__(256) void gn2_silu(
    float* __restrict__ buf, const float* __restrict__ gs, const float* __restrict__ gb)
{
    __shared__ float red[8];
    const int b = blockIdx.x >> 5;
    const int g = blockIdx.x & 31;
    const int tid = threadIdx.x;
    float* p = buf + ((size_t)(b*C_) + g*8) * 256;

    float vals[8];
    float s1 = 0.f, s2 = 0.f;
    #pragma unroll
    for (int cc = 0; cc < 8; ++cc) {
        const float v = p[cc*256 + tid];
        vals[cc] = v;
        s1 += v; s2 += v*v;
    }
    #pragma unroll
    for (int off = 32; off > 0; off >>= 1) {
        s1 += __shfl_down(s1, off);
        s2 += __shfl_down(s2, off);
    }
    const int lane = tid & 63, wid = tid >> 6;
    if (lane == 0) { red[wid] = s1; red[4 + wid] = s2; }
    __syncthreads();
    s1 = red[0] + red[1] + red[2] + red[3];
    s2 = red[4] + red[5] + red[6] + red[7];
    const float mean = s1 * (1.f/2048.f);
    const float var  = s2 * (1.f/2048.f) - mean*mean;
    const float rstd = rsqrtf(var + 1e-5f);
    #pragma unroll
    for (int cc = 0; cc < 8; ++cc) {
        const int c = g*8 + cc;
        const float xn = (vals[cc] - mean) * rstd * gs[c] + gb[c];
        const float y  = xn / (1.f + __expf(-xn));
        p[cc*256 + tid] = y;
    }
}

// ---------------------------------------------------------------------------
// MQA attention. One block per (b, head). K,V (256x32) staged in LDS.
// Each thread processes 2 Q-rows at a time (shares LDS reads), chunked
// online softmax (chunk of 8 keys).
// q layout: (B, C, 1024); k,v layout: (B, C, 256); out layout: (B, C, 1024)
// where channel = head*32 + d.
// ---------------------------------------------------------------------------
__global__ __launch_bounds__(256) void attention(
    const float* __restrict__ q, const float* __restrict__ k,
    const float* __restrict__ v, float* __restrict__ out)
{
    __shared__ float Ks[256][36];   // stride 36: rows 16B-aligned (b128 reads)
    __shared__ float Vs[256][36];
    const int b = blockIdx.x >> 3;
    const int h = blockIdx.x & 7;
    const int tid = threadIdx.x;

    const size_t kbase = ((size_t)(b*C_) + h*DH_) * (size_t)M_;
    #pragma unroll
    for (int d = 0; d < DH_; ++d) {
        Ks[tid][d] = k[kbase + (size_t)d * M_ + tid];
        Vs[tid][d] = v[kbase + (size_t)d * M_ + tid];
    }
    __syncthreads();

    const float scale = 0.17677669529663687f;  // 1/sqrt(32)
    const size_t qbase = ((size_t)(b*C_) + h*DH_) * (size_t)N_;

    for (int rt = 0; rt < 2; ++rt) {
        const int n0 = rt*512 + tid;
        const int n1 = n0 + 256;
        float qa[DH_], qb[DH_];
        #pragma unroll
        for (int d = 0; d < DH_; ++d) {
            qa[d] = q[qbase + (size_t)d * N_ + n0] * scale;
            qb[d] = q[qbase + (size_t)d * N_ + n1] * scale;
        }
        float ma = -1e30f, mb = -1e30f, la = 0.f, lb = 0.f;
        float aa[DH_], ab[DH_];
        #pragma unroll
        for (int d = 0; d < DH_; ++d) { aa[d] = 0.f; ab[d] = 0.f; }

        for (int m0 = 0; m0 < M_; m0 += 8) {
            float sa[8], sb[8];
            #pragma unroll
            for (int mm = 0; mm < 8; ++mm) {
                float da = 0.f, db = 0.f;
                #pragma unroll
                for (int d = 0; d < DH_; ++d) {
                    const float kv = Ks[m0 + mm][d];
                    da += qa[d] * kv;
                    db += qb[d] * kv;
                }
                sa[mm] = da; sb[mm] = db;
            }
            float ca = sa[0], cb = sb[0];
            #pragma unroll
            for (int mm = 1; mm < 8; ++mm) { ca = fmaxf(ca, sa[mm]); cb = fmaxf(cb, sb[mm]); }
            const float na = fmaxf(ma, ca), nb = fmaxf(mb, cb);
            const float ala = __expf(ma - na), alb = __expf(mb - nb);
            la *= ala; lb *= alb;
            #pragma unroll
            for (int d = 0; d < DH_; ++d) { aa[d] *= ala; ab[d] *= alb; }
            #pragma unroll
            for (int mm = 0; mm < 8; ++mm) {
                const float pa = __expf(sa[mm] - na);
                const float pb = __expf(sb[mm] - nb);
                la += pa; lb += pb;
                #pragma unroll
                for (int d = 0; d < DH_; ++d) {
                    const float vv = Vs[m0 + mm][d];
                    aa[d] += pa * vv;
                    ab[d] += pb * vv;
                }
            }
            ma = na; mb = nb;
        }
        const float ia = 1.f / la, ib = 1.f / lb;
        #pragma unroll
        for (int d = 0; d < DH_; ++d) {
            out[qbase + (size_t)d * N_ + n0] = aa[d] * ia;
            out[qbase + (size_t)d * N_ + n1] = ab[d] * ib;
        }
    }
}

// ---------------------------------------------------------------------------
extern "C" void kernel_launch(void* const* d_in, const int* in_sizes, int n_in,
                              void* d_out, int out_size, void* d_ws, size_t ws_size,
                              hipStream_t stream)
{
    const float* x    = (const float*)d_in[0];
    const float* wq   = (const float*)d_in[1];
    const float* bq   = (const float*)d_in[2];
    const float* wk   = (const float*)d_in[3];
    const float* bk   = (const float*)d_in[4];
    const float* wv   = (const float*)d_in[5];
    const float* bv   = (const float*)d_in[6];
    const float* kdw  = (const float*)d_in[7];
    const float* kg1s = (const float*)d_in[8];
    const float* kg1b = (const float*)d_in[9];
    const float* kpw  = (const float*)d_in[10];
    const float* kg2s = (const float*)d_in[11];
    const float* kg2b = (const float*)d_in[12];
    const float* vdw  = (const float*)d_in[13];
    const float* vg1s = (const float*)d_in[14];
    const float* vg1b = (const float*)d_in[15];
    const float* vpw  = (const float*)d_in[16];
    const float* vg2s = (const float*)d_in[17];
    const float* vg2b = (const float*)d_in[18];
    float* out = (float*)d_out;

    // workspace layout (floats): q | k0 | v0 | kd | vd | k2 | v2  = 128 MiB
    float* ws = (float*)d_ws;
    float* q  = ws;
    float* k0 = q  + (size_t)B_ * C_ * N_;
    float* v0 = k0 + (size_t)B_ * C_ * N_;
    float* kd = v0 + (size_t)B_ * C_ * N_;
    float* vd = kd + (size_t)B_ * C_ * M_;
    float* k2 = vd + (size_t)B_ * C_ * M_;
    float* v2 = k2 + (size_t)B_ * C_ * M_;

    dim3 blk(256);

    // q/k/v 1x1 convs (full res)
    gemm1x1<N_><<<dim3(4, 16, B_), blk, 0, stream>>>(wq, x, bq, q);
    gemm1x1<N_><<<dim3(4, 16, B_), blk, 0, stream>>>(wk, x, bk, k0);
    gemm1x1<N_><<<dim3(4, 16, B_), blk, 0, stream>>>(wv, x, bv, v0);

    // downsample branches: dwconv3x3 s2 + GN1 + SiLU
    dw_gn_silu<<<dim3(B_ * 32), blk, 0, stream>>>(k0, kdw, kg1s, kg1b, kd);
    dw_gn_silu<<<dim3(B_ * 32), blk, 0, stream>>>(v0, vdw, vg1s, vg1b, vd);

    // pointwise convs (16x16)
    gemm1x1<M_><<<dim3(4, 4, B_), blk, 0, stream>>>(kpw, kd, nullptr, k2);
    gemm1x1<M_><<<dim3(4, 4, B_), blk, 0, stream>>>(vpw, vd, nullptr, v2);

    // GN2 + SiLU (in place)
    gn2_silu<<<dim3(B_ * 32), blk, 0, stream>>>(k2, kg2s, kg2b);
    gn2_silu<<<dim3(B_ * 32), blk, 0, stream>>>(v2, vg2s, vg2b);

    // MQA attention
    attention<<<dim3(B_ * NH_), blk, 0, stream>>>(q, k2, v2, out);
}